// Round 9
// baseline (31.160 us; speedup 1.0000x reference)
//
#include <hip/hip_runtime.h>
#include <math.h>

#define N_ROWS 256
#define NB 8732
#define NB4 2183              // NB / 4 (exact)
#define CHUNKS 8              // 2048 blocks = 8/CU = one co-resident generation
#define TAILN (NB4 - CHUNKS * 256)   // 135 tail groups -> chunk 7, tid<135
#define SLOT_F 32             // floats per row slot (128 B own cache line)
#define WS_BYTES ((N_ROWS + 1) * 128)

typedef float f4 __attribute__((ext_vector_type(4)));
typedef int   i4 __attribute__((ext_vector_type(4)));

__device__ __forceinline__ float smooth_l1(float d) {
    float ad = fabsf(d);
    return ad < 1.0f ? 0.5f * d * d : ad - 0.5f;
}

// BCE with logits, y = 0 (used by fallback top-K path only; accurate version)
__device__ __forceinline__ float bce_y0(float x) {
    return fmaxf(x, 0.0f) + log1pf(expf(-fabsf(x)));
}

struct Batch {
    f4 p0, p1, p2, p3, q0, q1, q2, q3, d0, d1, d2, d3, px;
    i4 lb;
};

__device__ __forceinline__ Batch loadB(
    const f4* __restrict__ ploc4, const f4* __restrict__ gloc4,
    const f4* __restrict__ db4, const f4* __restrict__ pl4,
    const i4* __restrict__ gl4, int rb, int rs, int g) {
    Batch b;
    b.p0 = ploc4[rb + 0 * NB4 + g];
    b.p1 = ploc4[rb + 1 * NB4 + g];
    b.p2 = ploc4[rb + 2 * NB4 + g];
    b.p3 = ploc4[rb + 3 * NB4 + g];
    b.q0 = gloc4[rb + 0 * NB4 + g];
    b.q1 = gloc4[rb + 1 * NB4 + g];
    b.q2 = gloc4[rb + 2 * NB4 + g];
    b.q3 = gloc4[rb + 3 * NB4 + g];
    b.d0 = db4[0 * NB4 + g];
    b.d1 = db4[1 * NB4 + g];
    b.d2 = db4[2 * NB4 + g];
    b.d3 = db4[3 * NB4 + g];
    b.lb = gl4[rs + g];
    b.px = pl4[rs + g];
    return b;
}

__device__ __forceinline__ void accumB(const Batch& b, float& sl1, float& cAll,
                                       float& cPos, float& pCnt) {
#pragma unroll
    for (int k = 0; k < 4; ++k) {
        float rw2 = __builtin_amdgcn_rcpf(b.d2[k]);
        float rw3 = __builtin_amdgcn_rcpf(b.d3[k]);
        float gx = (b.q0[k] - b.d0[k]) * rw2;
        float gy = (b.q1[k] - b.d1[k]) * rw3;
        float gw = __logf(b.q2[k] * rw2);
        float gh = __logf(b.q3[k] * rw3);
        float s = smooth_l1(b.p0[k] - gx)
                + smooth_l1(b.p1[k] - gy)
                + smooth_l1(b.p2[k] - gw)
                + smooth_l1(b.p3[k] - gh);
        int lab = b.lb[k];
        float x = b.px[k];
        float con = fmaxf(x, 0.0f) - x * (float)lab
                  + __logf(1.0f + __expf(-fabsf(x)));
        cAll += con;
        float m = (lab > 0) ? 1.0f : 0.0f;
        pCnt += m;
        sl1 += m * s;
        cPos += m * con;
    }
}

// Single fused kernel. Partial phase identical to the proven R8 engine.
// Cross-block combine: non-returning slot atomics -> vmcnt(0) (same-XCD L2,
// ~100cy: row slots are only ever touched by one XCD because
// (row + 256*chunk) % 8 == row % 8) -> arrival counter; 8th arriver
// finalizes the row; 256th row-finalizer writes out[0].
__global__ __launch_bounds__(256) void fused_kernel(
    const float* __restrict__ ploc, const float* __restrict__ plabel,
    const float* __restrict__ gloc, const int* __restrict__ glabel,
    const float* __restrict__ dboxes, float* __restrict__ ws,
    float* __restrict__ out) {
    const int row = blockIdx.x;
    const int chunk = blockIdx.y;
    const int tid = threadIdx.x;
    const int g = chunk * 256 + tid;

    const f4* __restrict__ ploc4 = (const f4*)ploc;
    const f4* __restrict__ gloc4 = (const f4*)gloc;
    const f4* __restrict__ db4   = (const f4*)dboxes;
    const f4* __restrict__ pl4   = (const f4*)plabel;
    const i4* __restrict__ gl4   = (const i4*)glabel;

    const int rb = row * 4 * NB4;
    const int rs = row * NB4;

    float sl1acc = 0.0f, conAll = 0.0f, conPos = 0.0f, posCnt = 0.0f;

    {
        Batch b = loadB(ploc4, gloc4, db4, pl4, gl4, rb, rs, g);
        accumB(b, sl1acc, conAll, conPos, posCnt);
    }
    if (chunk == CHUNKS - 1 && tid < TAILN) {
        Batch b = loadB(ploc4, gloc4, db4, pl4, gl4, rb, rs, CHUNKS * 256 + tid);
        accumB(b, sl1acc, conAll, conPos, posCnt);
    }

    // block reduction: wave64 shuffle, then LDS across 4 waves
    float v0 = sl1acc, v1 = conAll, v2 = conPos, v3 = posCnt;
#pragma unroll
    for (int off = 32; off > 0; off >>= 1) {
        v0 += __shfl_down(v0, off);
        v1 += __shfl_down(v1, off);
        v2 += __shfl_down(v2, off);
        v3 += __shfl_down(v3, off);
    }
    __shared__ float sm[4][4];
    const int wid = tid >> 6, lane = tid & 63;
    if (lane == 0) {
        sm[wid][0] = v0; sm[wid][1] = v1; sm[wid][2] = v2; sm[wid][3] = v3;
    }
    __syncthreads();
    if (wid != 0) return;

    float* slot = ws + row * SLOT_F;             // 128 B private line per row
    unsigned* rowcnt = (unsigned*)(slot + 4);
    float* gacc = ws + N_ROWS * SLOT_F;          // global accumulator line
    unsigned* gcnt = (unsigned*)(gacc + 4);

    if (lane < 4) {
        float v = sm[0][lane] + sm[1][lane] + sm[2][lane] + sm[3][lane];
        atomicAdd(&slot[lane], v);               // fire-and-forget value RMWs
    }
    // own RMWs committed at coherence point before signaling arrival
    asm volatile("s_waitcnt vmcnt(0)" ::: "memory");
    unsigned arr = 0u;
    if (lane == 0) arr = atomicAdd(rowcnt, 1u);
    arr = __shfl(arr, 0);
    if (arr != CHUNKS - 1) return;               // not the row's last arriver

    // ---- row finalize (one block per row reaches here) ----
    float rv = 0.0f;
    if (lane < 4) rv = atomicAdd(&slot[lane], 0.0f);  // coherent read
    float sl1  = __shfl(rv, 0);
    float cAll = __shfl(rv, 1);
    float cPos = __shfl(rv, 2);
    float posf = __shfl(rv, 3);
    if (lane != 0) return;

    const int pos = (int)(posf + 0.5f);
    const long long K = 3LL * (long long)pos;
    float closs;
    if (pos == 0) {
        closs = 0.0f;
    } else if (K >= (long long)NB) {
        closs = cAll;                            // neg_mask selects everything
    } else {
        // hard-negative-mining fallback (dead for this data): top-K negative
        // con via radix search on the uint bit pattern (con >= 0).
        const int Ki = (int)K;
        const float* plRow = plabel + row * NB;
        const int* glRow = glabel + row * NB;
        unsigned cur = 0;
        for (int bit = 31; bit >= 0; --bit) {
            unsigned trial = cur | (1u << bit);
            int c2 = 0;
            for (int j = 0; j < NB; ++j) {
                if (glRow[j] > 0) continue;
                float con = bce_y0(plRow[j]);
                if (__float_as_uint(con) >= trial) c2++;
            }
            if (c2 >= Ki) cur = trial;
        }
        const float thr = __uint_as_float(cur);
        int cntG = 0; float sumG = 0.f;
        for (int j = 0; j < NB; ++j) {
            if (glRow[j] > 0) continue;
            float con = bce_y0(plRow[j]);
            if (con > thr) { cntG++; sumG += con; }
        }
        closs = cPos + sumG + (float)(Ki - cntG) * thr;
    }
    float loss = (pos > 0) ? (sl1 + closs) / (float)pos : 0.0f;

    atomicAdd(gacc, loss * (1.0f / 256.0f));     // fire-and-forget
    asm volatile("s_waitcnt vmcnt(0)" ::: "memory");
    unsigned g2 = atomicAdd(gcnt, 1u);
    if (g2 == N_ROWS - 1) {
        out[0] = atomicAdd(gacc, 0.0f);          // coherent read of final mean
    }
}

extern "C" void kernel_launch(void* const* d_in, const int* in_sizes, int n_in,
                              void* d_out, int out_size, void* d_ws, size_t ws_size,
                              hipStream_t stream) {
    const float* ploc   = (const float*)d_in[0];
    const float* plabel = (const float*)d_in[1];
    const float* gloc   = (const float*)d_in[2];
    const int*   glabel = (const int*)d_in[3];
    const float* dboxes = (const float*)d_in[4];
    float* ws  = (float*)d_ws;
    float* out = (float*)d_out;

    // replay-safe zero of slots + counters + global acc (single memset node)
    hipMemsetAsync(ws, 0, WS_BYTES, stream);

    dim3 grid(N_ROWS, CHUNKS);
    hipLaunchKernelGGL(fused_kernel, grid, dim3(256), 0, stream,
                       ploc, plabel, gloc, glabel, dboxes, ws, out);
}

// Round 10
// 22.213 us; speedup vs baseline: 1.4028x; 1.4028x over previous
//
#include <hip/hip_runtime.h>
#include <math.h>

#define N_ROWS 256
#define NB 8732
#define NB4 2183              // NB / 4 (exact)
#define CHUNKS 4              // 4 chunks x 512 groups; tail 135 -> chunk 3
#define TAILG 2048            // tail groups start
#define TAILN (NB4 - TAILG)   // 135

typedef float f4 __attribute__((ext_vector_type(4)));
typedef int   i4 __attribute__((ext_vector_type(4)));

__device__ __forceinline__ float smooth_l1(float d) {
    float ad = fabsf(d);
    return ad < 1.0f ? 0.5f * d * d : ad - 0.5f;
}

// BCE with logits, y = 0 (used by fallback top-K path only; accurate version)
__device__ __forceinline__ float bce_y0(float x) {
    return fmaxf(x, 0.0f) + log1pf(expf(-fabsf(x)));
}

struct Batch {
    f4 p0, p1, p2, p3, q0, q1, q2, q3, d0, d1, d2, d3, px;
    i4 lb;
};

__device__ __forceinline__ Batch loadB(
    const f4* __restrict__ ploc4, const f4* __restrict__ gloc4,
    const f4* __restrict__ db4, const f4* __restrict__ pl4,
    const i4* __restrict__ gl4, int rb, int rs, int g) {
    Batch b;
    b.p0 = ploc4[rb + 0 * NB4 + g];
    b.p1 = ploc4[rb + 1 * NB4 + g];
    b.p2 = ploc4[rb + 2 * NB4 + g];
    b.p3 = ploc4[rb + 3 * NB4 + g];
    b.q0 = gloc4[rb + 0 * NB4 + g];
    b.q1 = gloc4[rb + 1 * NB4 + g];
    b.q2 = gloc4[rb + 2 * NB4 + g];
    b.q3 = gloc4[rb + 3 * NB4 + g];
    b.d0 = db4[0 * NB4 + g];
    b.d1 = db4[1 * NB4 + g];
    b.d2 = db4[2 * NB4 + g];
    b.d3 = db4[3 * NB4 + g];
    b.lb = gl4[rs + g];
    b.px = pl4[rs + g];
    return b;
}

__device__ __forceinline__ void accumB(const Batch& b, float& sl1, float& cAll,
                                       float& cPos, float& pCnt) {
#pragma unroll
    for (int k = 0; k < 4; ++k) {
        float rw2 = __builtin_amdgcn_rcpf(b.d2[k]);
        float rw3 = __builtin_amdgcn_rcpf(b.d3[k]);
        float gx = (b.q0[k] - b.d0[k]) * rw2;
        float gy = (b.q1[k] - b.d1[k]) * rw3;
        float gw = __logf(b.q2[k] * rw2);
        float gh = __logf(b.q3[k] * rw3);
        float s = smooth_l1(b.p0[k] - gx)
                + smooth_l1(b.p1[k] - gy)
                + smooth_l1(b.p2[k] - gw)
                + smooth_l1(b.p3[k] - gh);
        int lab = b.lb[k];
        float x = b.px[k];
        float con = fmaxf(x, 0.0f) - x * (float)lab
                  + __logf(1.0f + __expf(-fabsf(x)));
        cAll += con;
        float m = (lab > 0) ? 1.0f : 0.0f;
        pCnt += m;
        sl1 += m * s;
        cPos += m * con;
    }
}

// grid (256 rows x 4 chunks) x 256 thr = 1024 blocks = 4/CU.
// Two groups per thread, software-pipelined: batch-b loads issue before
// batch-a compute (b's 14 loads in flight during accumB(a)).
// NOTE: no min-waves launch bound — two live Batch structs are ~112 VGPR;
// a (..., >=4) bound would cap at 128 and spill to scratch (R5/R7 lesson).
__global__ __launch_bounds__(256) void partial_kernel(
    const float* __restrict__ ploc, const float* __restrict__ plabel,
    const float* __restrict__ gloc, const int* __restrict__ glabel,
    const float* __restrict__ dboxes, float* __restrict__ ws) {
    const int row = blockIdx.x;
    const int chunk = blockIdx.y;
    const int tid = threadIdx.x;
    const int base = chunk * 512;

    const f4* __restrict__ ploc4 = (const f4*)ploc;
    const f4* __restrict__ gloc4 = (const f4*)gloc;
    const f4* __restrict__ db4   = (const f4*)dboxes;
    const f4* __restrict__ pl4   = (const f4*)plabel;
    const i4* __restrict__ gl4   = (const i4*)glabel;

    const int rb = row * 4 * NB4;
    const int rs = row * NB4;

    float sl1acc = 0.0f, conAll = 0.0f, conPos = 0.0f, posCnt = 0.0f;

    Batch a = loadB(ploc4, gloc4, db4, pl4, gl4, rb, rs, base + tid);
    Batch b = loadB(ploc4, gloc4, db4, pl4, gl4, rb, rs, base + 256 + tid);
    accumB(a, sl1acc, conAll, conPos, posCnt);
    if (chunk == CHUNKS - 1 && tid < TAILN) {
        Batch t = loadB(ploc4, gloc4, db4, pl4, gl4, rb, rs, TAILG + tid);
        accumB(b, sl1acc, conAll, conPos, posCnt);
        accumB(t, sl1acc, conAll, conPos, posCnt);
    } else {
        accumB(b, sl1acc, conAll, conPos, posCnt);
    }

    // block reduction: wave64 shuffle, then LDS across 4 waves
    float v0 = sl1acc, v1 = conAll, v2 = conPos, v3 = posCnt;
#pragma unroll
    for (int off = 32; off > 0; off >>= 1) {
        v0 += __shfl_down(v0, off);
        v1 += __shfl_down(v1, off);
        v2 += __shfl_down(v2, off);
        v3 += __shfl_down(v3, off);
    }
    __shared__ float sm[4][4];
    const int wid = tid >> 6, lane = tid & 63;
    if (lane == 0) {
        sm[wid][0] = v0; sm[wid][1] = v1; sm[wid][2] = v2; sm[wid][3] = v3;
    }
    __syncthreads();
    if (tid == 0) {
        f4 part;
        part.x = sm[0][0] + sm[1][0] + sm[2][0] + sm[3][0];
        part.y = sm[0][1] + sm[1][1] + sm[2][1] + sm[3][1];
        part.z = sm[0][2] + sm[1][2] + sm[2][2] + sm[3][2];
        part.w = sm[0][3] + sm[1][3] + sm[2][3] + sm[3][3];
        ((f4*)ws)[chunk * N_ROWS + row] = part;   // [chunk][row]: coalesced later
    }
}

__global__ __launch_bounds__(256) void final_kernel(
    const float* __restrict__ ws, const float* __restrict__ plabel,
    const int* __restrict__ glabel, float* __restrict__ out) {
    const int r = threadIdx.x;  // one thread per batch row
    float sl1 = 0.f, cAll = 0.f, cPos = 0.f, posf = 0.f;
#pragma unroll
    for (int c = 0; c < CHUNKS; ++c) {
        f4 p = ((const f4*)ws)[c * N_ROWS + r];
        sl1 += p.x; cAll += p.y; cPos += p.z; posf += p.w;
    }
    const int pos = (int)(posf + 0.5f);
    const long long K = 3LL * (long long)pos;

    float closs;
    if (pos == 0) {
        closs = 0.0f;
    } else if (K >= (long long)NB) {
        closs = cAll;                      // neg_mask selects everything
    } else {
        // hard-negative-mining fallback (dead for this data): top-K negative
        // con via radix search on the uint bit pattern (con >= 0).
        const int Ki = (int)K;
        const float* plRow = plabel + r * NB;
        const int* glRow = glabel + r * NB;
        unsigned cur = 0;
        for (int bit = 31; bit >= 0; --bit) {
            unsigned trial = cur | (1u << bit);
            int c2 = 0;
            for (int j = 0; j < NB; ++j) {
                if (glRow[j] > 0) continue;
                float con = bce_y0(plRow[j]);
                if (__float_as_uint(con) >= trial) c2++;
            }
            if (c2 >= Ki) cur = trial;
        }
        const float thr = __uint_as_float(cur);
        int cntG = 0; float sumG = 0.f;
        for (int j = 0; j < NB; ++j) {
            if (glRow[j] > 0) continue;
            float con = bce_y0(plRow[j]);
            if (con > thr) { cntG++; sumG += con; }
        }
        closs = cPos + sumG + (float)(Ki - cntG) * thr;
    }

    float loss = (pos > 0) ? (sl1 + closs) / (float)pos : 0.0f;

    // mean over 256 rows
#pragma unroll
    for (int off = 32; off > 0; off >>= 1) loss += __shfl_down(loss, off);
    __shared__ float sm[4];
    const int wid = threadIdx.x >> 6, lane = threadIdx.x & 63;
    if (lane == 0) sm[wid] = loss;
    __syncthreads();
    if (threadIdx.x == 0) {
        out[0] = (sm[0] + sm[1] + sm[2] + sm[3]) * (1.0f / 256.0f);
    }
}

extern "C" void kernel_launch(void* const* d_in, const int* in_sizes, int n_in,
                              void* d_out, int out_size, void* d_ws, size_t ws_size,
                              hipStream_t stream) {
    const float* ploc   = (const float*)d_in[0];
    const float* plabel = (const float*)d_in[1];
    const float* gloc   = (const float*)d_in[2];
    const int*   glabel = (const int*)d_in[3];
    const float* dboxes = (const float*)d_in[4];
    float* ws  = (float*)d_ws;
    float* out = (float*)d_out;

    dim3 grid(N_ROWS, CHUNKS);
    hipLaunchKernelGGL(partial_kernel, grid, dim3(256), 0, stream,
                       ploc, plabel, gloc, glabel, dboxes, ws);
    hipLaunchKernelGGL(final_kernel, dim3(1), dim3(256), 0, stream,
                       ws, plabel, glabel, out);
}